// Round 5
// baseline (1169.966 us; speedup 1.0000x reference)
//
#include <hip/hip_runtime.h>

// Problem constants (fixed by reference)
#define NE 8
#define TT 2048            // tokens per expert
#define KD 2048            // INPUT_SIZE  (K)
#define ND 8192            // OUTPUT_SIZE (N)
#define MT (NE * TT)       // 16384 total rows
#define NW ((size_t)NE * ND * KD)   // 134217728 weight elems
#define NX ((size_t)MT * KD)        // 33554432 input elems

typedef _Float16 f16;
typedef _Float16 f16x4 __attribute__((ext_vector_type(4)));
typedef _Float16 f16x8 __attribute__((ext_vector_type(8)));
typedef float    f32x4 __attribute__((ext_vector_type(4)));

// ---------------- K1: partial abs-sum (f64, deterministic) ----------------
__global__ void k_abs_partial(const float* __restrict__ w, double* __restrict__ part) {
    __shared__ double sred[256];
    const size_t n4 = NW / 4;
    const size_t stride = (size_t)gridDim.x * blockDim.x;
    double acc = 0.0;
    for (size_t i = (size_t)blockIdx.x * blockDim.x + threadIdx.x; i < n4; i += stride) {
        float4 v = ((const float4*)w)[i];
        acc += (double)fabsf(v.x) + (double)fabsf(v.y) + (double)fabsf(v.z) + (double)fabsf(v.w);
    }
    sred[threadIdx.x] = acc;
    __syncthreads();
    for (int s = 128; s > 0; s >>= 1) {
        if ((int)threadIdx.x < s) sred[threadIdx.x] += sred[threadIdx.x + s];
        __syncthreads();
    }
    if (threadIdx.x == 0) part[blockIdx.x] = sred[0];
}

// ---------------- K2: finalize scale ----------------
__global__ void k_finalize(const double* __restrict__ part, double* __restrict__ sc) {
    __shared__ double sred[256];
    double a = 0.0;
    for (int i = threadIdx.x; i < 2048; i += 256) a += part[i];
    sred[threadIdx.x] = a;
    __syncthreads();
    for (int s = 128; s > 0; s >>= 1) {
        if ((int)threadIdx.x < s) sred[threadIdx.x] += sred[threadIdx.x + s];
        __syncthreads();
    }
    if (threadIdx.x == 0) {
        double mean = sred[0] / (double)NW;
        double denom = mean > 1e-5 ? mean : 1e-5;
        sc[0] = 1.0 / denom;   // scale
        sc[1] = denom;         // 1/scale (output multiplier)
    }
}

// ---------------- K3: quantize w -> ternary f16 ----------------
__global__ void k_quant(const float* __restrict__ w, const double* __restrict__ sc,
                        f16* __restrict__ q) {
    const double scale = sc[0];
    const size_t n4 = NW / 4;
    const size_t stride = (size_t)gridDim.x * blockDim.x;
    for (size_t i = (size_t)blockIdx.x * blockDim.x + threadIdx.x; i < n4; i += stride) {
        float4 v = ((const float4*)w)[i];
        f16x4 o;
        o[0] = (f16)(float)fmin(fmax(rint((double)v.x * scale), -1.0), 1.0);
        o[1] = (f16)(float)fmin(fmax(rint((double)v.y * scale), -1.0), 1.0);
        o[2] = (f16)(float)fmin(fmax(rint((double)v.z * scale), -1.0), 1.0);
        o[3] = (f16)(float)fmin(fmax(rint((double)v.w * scale), -1.0), 1.0);
        ((f16x4*)q)[i] = o;
    }
}

// ---------------- K4: x f32 -> f16 ----------------
__global__ void k_xconv(const float* __restrict__ x, f16* __restrict__ xh) {
    const size_t n4 = NX / 4;
    const size_t stride = (size_t)gridDim.x * blockDim.x;
    for (size_t i = (size_t)blockIdx.x * blockDim.x + threadIdx.x; i < n4; i += stride) {
        float4 v = ((const float4*)x)[i];
        f16x4 o;
        o[0] = (f16)v.x; o[1] = (f16)v.y; o[2] = (f16)v.z; o[3] = (f16)v.w;
        ((f16x4*)xh)[i] = o;
    }
}

// ---------------- K5: grouped GEMM, 128x128x64, 4 waves, 64 KiB LDS -------
// 2 blocks/CU (de-lockstepped barriers) is the point of this geometry.
// Buffer (32 KiB): [A-k0 | A-k1 | B-k0 | B-k1] x 8 KiB; two buffers.
// Uniform phase: {8 ds_read | 4 global_load_lds | BAR | lgkmcnt(0)+schedbar |
//                 16 MFMA (setprio) | VM(4) | BAR}
// vmcnt(4): at each phase end exactly 8 staging loads are outstanding; the 4
// oldest (the half needed next phase) must land. NEVER nonzero imm offset on
// global_load_lds (it shifts BOTH global and LDS addresses -> round-4 NaN);
// k-advance lives in pointers, bumped +64B/phase behind an opaque asm so the
// backend cannot re-fold the add into the instruction offset.
#define NTK 32   // KD / 64

__device__ __forceinline__ void gload16(const void* g, void* l) {
    __builtin_amdgcn_global_load_lds(
        (const __attribute__((address_space(1))) unsigned int*)g,
        (__attribute__((address_space(3))) unsigned int*)l, 16, 0, 0);
}

#define BAR() __builtin_amdgcn_s_barrier()
#define LGKM0() do { asm volatile("s_waitcnt lgkmcnt(0)" ::: "memory"); \
                     __builtin_amdgcn_sched_barrier(0); } while (0)
#define VM(N) asm volatile("s_waitcnt vmcnt(" #N ")" ::: "memory")

// advance the 4 staging pointers by one k-half (64 B); opaque to ISel
#define ADV() do { gA0 += 64; gA1 += 64; gB0 += 64; gB1 += 64; \
    asm volatile("" : "+v"(gA0), "+v"(gA1), "+v"(gB0), "+v"(gB1)); } while (0)

// per-wave fragment reads: base + compile-time imm only
#define RD_AB(RB, KH) { \
  _Pragma("unroll") for (int i_ = 0; i_ < 4; ++i_) \
    af[i_] = *(const f16x8*)(aR + (RB) + (KH) * 8192 + i_ * 1024); \
  _Pragma("unroll") for (int i_ = 0; i_ < 4; ++i_) \
    bf[i_] = *(const f16x8*)(bR + (RB) + (KH) * 8192 + i_ * 1024); }

// stage one k-half (A 8 KiB + B 8 KiB) into buffer SB
#define STG_H(SB, KH) do { \
    gload16(gA0, dst0 + (SB) + (KH) * 8192); \
    gload16(gA1, dst0 + (SB) + (KH) * 8192 + 1024); \
    gload16(gB0, dst0 + (SB) + (KH) * 8192 + 16384); \
    gload16(gB1, dst0 + (SB) + (KH) * 8192 + 17408); \
} while (0)

#define MFMA_H() { \
  __builtin_amdgcn_s_setprio(1); \
  _Pragma("unroll") for (int m_ = 0; m_ < 4; ++m_) \
    _Pragma("unroll") for (int n_ = 0; n_ < 4; ++n_) \
      acc[m_][n_] = __builtin_amdgcn_mfma_f32_16x16x32_f16( \
          af[m_], bf[n_], acc[m_][n_], 0, 0, 0); \
  __builtin_amdgcn_s_setprio(0); }

// one K-tile (two phases), reading buf RB, staging next tile into buf SB
#define TILE_S(RB, SB) do { \
    RD_AB(RB, 0); STG_H(SB, 0); ADV(); \
    BAR(); LGKM0(); MFMA_H(); VM(4); BAR(); \
    RD_AB(RB, 1); STG_H(SB, 1); ADV(); \
    BAR(); LGKM0(); MFMA_H(); VM(4); BAR(); \
} while (0)

#define TILE_LAST(RB) do { \
    RD_AB(RB, 0); \
    BAR(); LGKM0(); MFMA_H(); VM(0); BAR(); \
    RD_AB(RB, 1); \
    LGKM0(); MFMA_H(); \
} while (0)

__global__ __launch_bounds__(256, 2)
void k_gemm(const f16* __restrict__ xh, const f16* __restrict__ qh,
            const double* __restrict__ sc, float* __restrict__ out) {
    __shared__ char lds[2 * 32768];   // 64 KiB -> 2 blocks/CU

    const int lane = (int)threadIdx.x & 63;
    const int wid  = (int)threadIdx.x >> 6;   // 0..3
    const int wr   = wid >> 1;                 // 0..1 (M strip of 64)
    const int wc   = wid & 1;                  // 0..1 (N strip of 64)
    const int li   = lane & 15;
    const int sl   = lane >> 4;                // k-slot 0..3

    // XCD-aware swizzle: nwg = 8192, divisible by 8; expert == XCD
    const int wg = ((int)blockIdx.x & 7) * 1024 + ((int)blockIdx.x >> 3);
    const int e  = wg >> 10;
    const int u  = wg & 1023;
    const int mt = (u >> 1) & 15;                  // 0..15
    const int nt = (((u >> 5) << 1) | (u & 1));    // 0..63 (2-wide windows)

    const f16* Ab = xh + ((size_t)e * TT + (size_t)mt * 128) * KD;
    const f16* Bb = qh + ((size_t)e * ND + (size_t)nt * 128) * KD;
    float*     Cb = out + ((size_t)e * TT + (size_t)mt * 128) * ND + (size_t)nt * 128;

    const float sfac = (float)sc[1];
    asm volatile("s_waitcnt vmcnt(0)" ::: "memory");

    // read-side bases: swizzle phase p = sl ^ (li&3) ^ ((li>>2)&3), lane-const
    const int pA = (sl ^ (lane & 3) ^ ((lane >> 2) & 3)) & 3;
    const char* aR = (const char*)lds + ((wr * 64 + li) << 6) + (pA << 4);
    const char* bR = (const char*)lds + 16384 + ((wc * 64 + li) << 6) + (pA << 4);

    // staging: 2 chunks (1 KiB) per wave per region; inverse-swizzled source
    const int lslot = (lane & 3) ^ ((lane >> 2) & 3) ^ ((lane >> 4) & 3);
    char* dst0 = (char*)lds + wid * 2048;
    const int srow0 = (wid * 2 + 0) * 16 + (lane >> 2);   // 0..127
    const int srow1 = (wid * 2 + 1) * 16 + (lane >> 2);
    const char* gA0 = (const char*)(Ab + (size_t)srow0 * KD + lslot * 8);
    const char* gA1 = (const char*)(Ab + (size_t)srow1 * KD + lslot * 8);
    const char* gB0 = (const char*)(Bb + (size_t)srow0 * KD + lslot * 8);
    const char* gB1 = (const char*)(Bb + (size_t)srow1 * KD + lslot * 8);

    f32x4 acc[4][4];
#pragma unroll
    for (int m = 0; m < 4; ++m)
#pragma unroll
        for (int n = 0; n < 4; ++n) acc[m][n] = (f32x4){0.f, 0.f, 0.f, 0.f};

    f16x8 af[4], bf[4];

    // prologue: stage tile 0 (both halves) into buf0
    STG_H(0, 0); ADV();
    STG_H(0, 1); ADV();
    VM(4);   // k0 of tile 0 landed (k1 still in flight)
    BAR();

    // tiles 0..29 (2 per iteration), 30, 31
    for (int t2 = 0; t2 < 15; ++t2) {
        TILE_S(0, 32768);       // even tile: read buf0, stage buf1
        TILE_S(32768, 0);       // odd tile: read buf1, stage buf0
    }
    TILE_S(0, 32768);           // tile 30
    TILE_LAST(32768);           // tile 31

    // ---- epilogue: scale by 1/scale, f32 store ----
#pragma unroll
    for (int m = 0; m < 4; ++m)
#pragma unroll
        for (int n = 0; n < 4; ++n)
#pragma unroll
            for (int r4 = 0; r4 < 4; ++r4) {
                const int row = wr * 64 + m * 16 + sl * 4 + r4;
                const int col = wc * 64 + n * 16 + li;
                Cb[(size_t)row * ND + col] = acc[m][n][r4] * sfac;
            }
}

// ---------------- fallback (only if ws too small): f32 tiled, on-the-fly quant ----------------
__global__ void k_fallback(const float* __restrict__ x, const float* __restrict__ w,
                           const double* __restrict__ sc, float* __restrict__ out) {
    const int row0 = blockIdx.x * 16;
    const int col0 = blockIdx.y * 16;
    const int e = row0 / TT;
    __shared__ float xs[16][17];
    __shared__ float wq[16][17];
    const double scale = sc[0];
    const float s = (float)sc[1];
    const int tx = threadIdx.x, ty = threadIdx.y;
    const float* wbase = w + ((size_t)e * ND + col0) * KD;
    float acc = 0.f;
    for (int k0 = 0; k0 < KD; k0 += 16) {
        xs[ty][tx] = x[(size_t)(row0 + ty) * KD + k0 + tx];
        const float wv = wbase[(size_t)ty * KD + k0 + tx];
        wq[ty][tx] = (float)fmin(fmax(rint((double)wv * scale), -1.0), 1.0);
        __syncthreads();
#pragma unroll
        for (int kk = 0; kk < 16; ++kk) acc += xs[ty][kk] * wq[tx][kk];
        __syncthreads();
    }
    out[(size_t)(row0 + ty) * ND + col0 + tx] = acc * s;
}

// ---------------- launch ----------------
extern "C" void kernel_launch(void* const* d_in, const int* in_sizes, int n_in,
                              void* d_out, int out_size, void* d_ws, size_t ws_size,
                              hipStream_t stream) {
    const float* x = (const float*)d_in[0];
    const float* w = (const float*)d_in[1];
    float* out = (float*)d_out;

    double* part = (double*)d_ws;                       // 2048 * 8 B
    double* sc   = (double*)((char*)d_ws + 16384);      // [0]=scale, [1]=1/scale

    const size_t need = 65536 + NX * 2 + NW * 2;        // ~320 MiB

    hipLaunchKernelGGL(k_abs_partial, dim3(2048), dim3(256), 0, stream, w, part);
    hipLaunchKernelGGL(k_finalize,   dim3(1),    dim3(256), 0, stream, part, sc);

    if (ws_size >= need) {
        f16* xh = (f16*)((char*)d_ws + 65536);
        f16* qh = (f16*)((char*)d_ws + 65536 + NX * 2);
        hipLaunchKernelGGL(k_quant, dim3(2048), dim3(256), 0, stream, w, sc, qh);
        hipLaunchKernelGGL(k_xconv, dim3(2048), dim3(256), 0, stream, x, xh);
        hipLaunchKernelGGL(k_gemm,  dim3(NE * (TT / 128) * (ND / 128)), dim3(256), 0, stream,
                           xh, qh, sc, out);
    } else {
        dim3 grid(MT / 16, ND / 16);
        hipLaunchKernelGGL(k_fallback, grid, dim3(16, 16), 0, stream, x, w, sc, out);
    }
}

// Round 6
// 887.899 us; speedup vs baseline: 1.3177x; 1.3177x over previous
//
#include <hip/hip_runtime.h>

// Problem constants (fixed by reference)
#define NE 8
#define TT 2048            // tokens per expert
#define KD 2048            // INPUT_SIZE  (K)
#define ND 8192            // OUTPUT_SIZE (N)
#define MT (NE * TT)       // 16384 total rows
#define NW ((size_t)NE * ND * KD)   // 134217728 weight elems
#define NX ((size_t)MT * KD)        // 33554432 input elems

typedef _Float16 f16;
typedef _Float16 f16x4 __attribute__((ext_vector_type(4)));
typedef _Float16 f16x8 __attribute__((ext_vector_type(8)));
typedef float    f32x4 __attribute__((ext_vector_type(4)));

// ---------------- K1: partial abs-sum (f64, deterministic) ----------------
__global__ void k_abs_partial(const float* __restrict__ w, double* __restrict__ part) {
    __shared__ double sred[256];
    const size_t n4 = NW / 4;
    const size_t stride = (size_t)gridDim.x * blockDim.x;
    double acc = 0.0;
    for (size_t i = (size_t)blockIdx.x * blockDim.x + threadIdx.x; i < n4; i += stride) {
        float4 v = ((const float4*)w)[i];
        acc += (double)fabsf(v.x) + (double)fabsf(v.y) + (double)fabsf(v.z) + (double)fabsf(v.w);
    }
    sred[threadIdx.x] = acc;
    __syncthreads();
    for (int s = 128; s > 0; s >>= 1) {
        if ((int)threadIdx.x < s) sred[threadIdx.x] += sred[threadIdx.x + s];
        __syncthreads();
    }
    if (threadIdx.x == 0) part[blockIdx.x] = sred[0];
}

// ---------------- K2: finalize scale ----------------
__global__ void k_finalize(const double* __restrict__ part, double* __restrict__ sc) {
    __shared__ double sred[256];
    double a = 0.0;
    for (int i = threadIdx.x; i < 2048; i += 256) a += part[i];
    sred[threadIdx.x] = a;
    __syncthreads();
    for (int s = 128; s > 0; s >>= 1) {
        if ((int)threadIdx.x < s) sred[threadIdx.x] += sred[threadIdx.x + s];
        __syncthreads();
    }
    if (threadIdx.x == 0) {
        double mean = sred[0] / (double)NW;
        double denom = mean > 1e-5 ? mean : 1e-5;
        sc[0] = 1.0 / denom;   // scale
        sc[1] = denom;         // 1/scale (output multiplier)
    }
}

// ---------------- K3: quantize w -> ternary f16 ----------------
__global__ void k_quant(const float* __restrict__ w, const double* __restrict__ sc,
                        f16* __restrict__ q) {
    const double scale = sc[0];
    const size_t n4 = NW / 4;
    const size_t stride = (size_t)gridDim.x * blockDim.x;
    for (size_t i = (size_t)blockIdx.x * blockDim.x + threadIdx.x; i < n4; i += stride) {
        float4 v = ((const float4*)w)[i];
        f16x4 o;
        o[0] = (f16)(float)fmin(fmax(rint((double)v.x * scale), -1.0), 1.0);
        o[1] = (f16)(float)fmin(fmax(rint((double)v.y * scale), -1.0), 1.0);
        o[2] = (f16)(float)fmin(fmax(rint((double)v.z * scale), -1.0), 1.0);
        o[3] = (f16)(float)fmin(fmax(rint((double)v.w * scale), -1.0), 1.0);
        ((f16x4*)q)[i] = o;
    }
}

// ---------------- K4: x f32 -> f16 ----------------
__global__ void k_xconv(const float* __restrict__ x, f16* __restrict__ xh) {
    const size_t n4 = NX / 4;
    const size_t stride = (size_t)gridDim.x * blockDim.x;
    for (size_t i = (size_t)blockIdx.x * blockDim.x + threadIdx.x; i < n4; i += stride) {
        float4 v = ((const float4*)x)[i];
        f16x4 o;
        o[0] = (f16)v.x; o[1] = (f16)v.y; o[2] = (f16)v.z; o[3] = (f16)v.w;
        ((f16x4*)xh)[i] = o;
    }
}

// ---------------- K5: grouped GEMM, 256x256x64, 8 waves, round-3 schedule
// with zero per-phase VALU address math.
// LDS: 2 buffers x [Ak0 | Ak1 | Bk0 | Bk1] x 16 KiB = 128 KiB.
// Phase = { ds_reads (base VGPR + compile-time imm) | stage 1 half (2 gloads,
//   per-lane pointers, IMM=0 always) | BAR | lgkmcnt(0)+sched_barrier |
//   setprio(1) 16 MFMA setprio(0) | [VM(4) at P1/P3] BAR }
// VM(4) cadence proven in round 3: at end-P1/end-P3 exactly 8 loads
// outstanding; waiting to 4 lands the 2 halves needed over the next 2 phases.
// Pointer bumps (+64 B per half) go through opaque asm so the backend can
// never fold them into the gload offset field (round-4 NaN: the intrinsic's
// IMM shifts BOTH global and LDS addresses).
#define NTK 32   // KD / 64

__device__ __forceinline__ void gload16(const void* g, void* l) {
    __builtin_amdgcn_global_load_lds(
        (const __attribute__((address_space(1))) unsigned int*)g,
        (__attribute__((address_space(3))) unsigned int*)l, 16, 0, 0);
}

#define BAR() __builtin_amdgcn_s_barrier()
#define LGKM0() do { asm volatile("s_waitcnt lgkmcnt(0)" ::: "memory"); \
                     __builtin_amdgcn_sched_barrier(0); } while (0)
#define VM(N) asm volatile("s_waitcnt vmcnt(" #N ")" ::: "memory")

// fragment reads: base VGPR + compile-time imm (max 23552, fits 16-bit DS imm)
#define RD_A(AR, KH, MOFF) { _Pragma("unroll") for (int i_ = 0; i_ < 4; ++i_) \
    af[i_] = *(const f16x8*)((AR) + ((KH) * 16384 + (MOFF) * 64 + i_ * 1024)); }
#define RD_B(BR, KH) { _Pragma("unroll") for (int i_ = 0; i_ < 4; ++i_) \
    bf[i_] = *(const f16x8*)((BR) + ((KH) * 16384 + i_ * 1024)); }

// stage one 16-KiB half (2 gloads), then advance that matrix's pointers +64 B
#define STG_A(SB, KH) do { \
    gload16(gA0, dst0 + (SB) + (KH) * 16384); \
    gload16(gA1, dst0 + (SB) + (KH) * 16384 + 1024); \
    gA0 += 64; gA1 += 64; \
    asm volatile("" : "+v"(gA0), "+v"(gA1)); } while (0)
#define STG_B(SB, KH) do { \
    gload16(gB0, dst0 + (SB) + 32768 + (KH) * 16384); \
    gload16(gB1, dst0 + (SB) + 32768 + (KH) * 16384 + 1024); \
    gB0 += 64; gB1 += 64; \
    asm volatile("" : "+v"(gB0), "+v"(gB1)); } while (0)

#define MFMA_Q(MB) { \
  __builtin_amdgcn_s_setprio(1); \
  _Pragma("unroll") for (int m_ = 0; m_ < 4; ++m_) \
    _Pragma("unroll") for (int n_ = 0; n_ < 4; ++n_) \
      acc[(MB) + m_][n_] = __builtin_amdgcn_mfma_f32_16x16x32_f16( \
          af[m_], bf[n_], acc[(MB) + m_][n_], 0, 0, 0); \
  __builtin_amdgcn_s_setprio(0); }

// one K-tile: 4 phases, reading buffer at AR/BR, staging next tile into SB
#define TILE_S(AR, BR, SB) do { \
    RD_A(AR, 0, 0); RD_B(BR, 0); \
    STG_A(SB, 0); \
    BAR(); LGKM0(); MFMA_Q(0); BAR(); \
    RD_A(AR, 0, 64); \
    STG_B(SB, 0); \
    BAR(); LGKM0(); MFMA_Q(4); VM(4); BAR(); \
    RD_A(AR, 1, 0); RD_B(BR, 1); \
    STG_A(SB, 1); \
    BAR(); LGKM0(); MFMA_Q(0); BAR(); \
    RD_A(AR, 1, 64); \
    STG_B(SB, 1); \
    BAR(); LGKM0(); MFMA_Q(4); VM(4); BAR(); \
} while (0)

#define TILE_LAST(AR, BR) do { \
    RD_A(AR, 0, 0); RD_B(BR, 0); \
    BAR(); LGKM0(); MFMA_Q(0); BAR(); \
    RD_A(AR, 0, 64); \
    BAR(); LGKM0(); MFMA_Q(4); VM(0); BAR(); \
    RD_A(AR, 1, 0); RD_B(BR, 1); \
    BAR(); LGKM0(); MFMA_Q(0); BAR(); \
    RD_A(AR, 1, 64); \
    BAR(); LGKM0(); MFMA_Q(4); \
} while (0)

__global__ __launch_bounds__(512, 2)
void k_gemm(const f16* __restrict__ xh, const f16* __restrict__ qh,
            const double* __restrict__ sc, float* __restrict__ out) {
    __shared__ char lds[2 * 65536];

    const int lane = (int)threadIdx.x & 63;
    const int wid  = (int)threadIdx.x >> 6;   // 0..7
    const int wr   = wid >> 2;                 // 0..1  (M strip of 128)
    const int wc   = wid & 3;                  // 0..3  (N strip of 64)
    const int li   = lane & 15;
    const int sl   = lane >> 4;                // k-slot 0..3

    // XCD-aware swizzle: nwg = 2048, divisible by 8; expert == XCD
    const int wg = ((int)blockIdx.x & 7) * 256 + ((int)blockIdx.x >> 3);
    const int e  = wg >> 8;
    const int u  = wg & 255;
    const int mt = (u >> 1) & 7;
    const int nt = (((u >> 4) << 1) | (u & 1));

    const f16* Ab = xh + ((size_t)e * TT + (size_t)mt * 256) * KD;
    const f16* Bb = qh + ((size_t)e * ND + (size_t)nt * 256) * KD;
    float*     Cb = out + ((size_t)e * TT + (size_t)mt * 256) * ND + (size_t)nt * 256;

    const float sfac = (float)sc[1];
    asm volatile("s_waitcnt vmcnt(0)" ::: "memory");

    // read-side bases: swizzle phase p = sl ^ (li&3) ^ ((li>>2)&3) is
    // lane-constant (fragment rows are 16-aligned-base + li)
    const int pA = (sl ^ (lane & 3) ^ ((lane >> 2) & 3)) & 3;
    const char* aR0 = (const char*)lds + ((wr * 128 + li) << 6) + (pA << 4);
    const char* bR0 = (const char*)lds + 32768 + ((wc * 64 + li) << 6) + (pA << 4);
    const char* aR1 = aR0 + 65536;
    const char* bR1 = bR0 + 65536;

    // staging: per-lane global pointers (2 x 1-KiB chunks per wave per half),
    // inverse-swizzled source so linear LDS dest + swizzled read agree
    const int lslot = (lane & 3) ^ ((lane >> 2) & 3) ^ ((lane >> 4) & 3);
    char* dst0 = (char*)lds + wid * 2048;
    const int srow0 = (wid * 2 + 0) * 16 + (lane >> 2);   // 0..255
    const int srow1 = (wid * 2 + 1) * 16 + (lane >> 2);
    const char* gA0 = (const char*)(Ab + (size_t)srow0 * KD + lslot * 8);
    const char* gA1 = (const char*)(Ab + (size_t)srow1 * KD + lslot * 8);
    const char* gB0 = (const char*)(Bb + (size_t)srow0 * KD + lslot * 8);
    const char* gB1 = (const char*)(Bb + (size_t)srow1 * KD + lslot * 8);

    f32x4 acc[8][4];
#pragma unroll
    for (int m = 0; m < 8; ++m)
#pragma unroll
        for (int n = 0; n < 4; ++n) acc[m][n] = (f32x4){0.f, 0.f, 0.f, 0.f};

    f16x8 af[4], bf[4];

    // prologue: stage tile 0 into buf0 (order Ak0,Bk0,Ak1,Bk1), wait k0 halves
    STG_A(0, 0);
    STG_B(0, 0);
    STG_A(0, 1);
    STG_B(0, 1);
    VM(4);
    BAR();

    // tiles 0..29 (2 per iteration), then 30, 31
    for (int t2 = 0; t2 < 15; ++t2) {
        TILE_S(aR0, bR0, 65536);    // even tile: read buf0, stage buf1
        TILE_S(aR1, bR1, 0);        // odd tile:  read buf1, stage buf0
    }
    TILE_S(aR0, bR0, 65536);        // tile 30, stage tile 31
    TILE_LAST(aR1, bR1);            // tile 31

    // ---- epilogue: scale by 1/scale, f32 store ----
#pragma unroll
    for (int m = 0; m < 8; ++m)
#pragma unroll
        for (int n = 0; n < 4; ++n)
#pragma unroll
            for (int r4 = 0; r4 < 4; ++r4) {
                const int row = wr * 128 + m * 16 + sl * 4 + r4;
                const int col = wc * 64 + n * 16 + li;
                Cb[(size_t)row * ND + col] = acc[m][n][r4] * sfac;
            }
}

// ---------------- fallback (only if ws too small): f32 tiled, on-the-fly quant ----------------
__global__ void k_fallback(const float* __restrict__ x, const float* __restrict__ w,
                           const double* __restrict__ sc, float* __restrict__ out) {
    const int row0 = blockIdx.x * 16;
    const int col0 = blockIdx.y * 16;
    const int e = row0 / TT;
    __shared__ float xs[16][17];
    __shared__ float wq[16][17];
    const double scale = sc[0];
    const float s = (float)sc[1];
    const int tx = threadIdx.x, ty = threadIdx.y;
    const float* wbase = w + ((size_t)e * ND + col0) * KD;
    float acc = 0.f;
    for (int k0 = 0; k0 < KD; k0 += 16) {
        xs[ty][tx] = x[(size_t)(row0 + ty) * KD + k0 + tx];
        const float wv = wbase[(size_t)ty * KD + k0 + tx];
        wq[ty][tx] = (float)fmin(fmax(rint((double)wv * scale), -1.0), 1.0);
        __syncthreads();
#pragma unroll
        for (int kk = 0; kk < 16; ++kk) acc += xs[ty][kk] * wq[tx][kk];
        __syncthreads();
    }
    out[(size_t)(row0 + ty) * ND + col0 + tx] = acc * s;
}

// ---------------- launch ----------------
extern "C" void kernel_launch(void* const* d_in, const int* in_sizes, int n_in,
                              void* d_out, int out_size, void* d_ws, size_t ws_size,
                              hipStream_t stream) {
    const float* x = (const float*)d_in[0];
    const float* w = (const float*)d_in[1];
    float* out = (float*)d_out;

    double* part = (double*)d_ws;                       // 2048 * 8 B
    double* sc   = (double*)((char*)d_ws + 16384);      // [0]=scale, [1]=1/scale

    const size_t need = 65536 + NX * 2 + NW * 2;        // ~320 MiB

    hipLaunchKernelGGL(k_abs_partial, dim3(2048), dim3(256), 0, stream, w, part);
    hipLaunchKernelGGL(k_finalize,   dim3(1),    dim3(256), 0, stream, part, sc);

    if (ws_size >= need) {
        f16* xh = (f16*)((char*)d_ws + 65536);
        f16* qh = (f16*)((char*)d_ws + 65536 + NX * 2);
        hipLaunchKernelGGL(k_quant, dim3(2048), dim3(256), 0, stream, w, sc, qh);
        hipLaunchKernelGGL(k_xconv, dim3(2048), dim3(256), 0, stream, x, xh);
        hipLaunchKernelGGL(k_gemm,  dim3(NE * (TT / 256) * (ND / 256)), dim3(512), 0, stream,
                           xh, qh, sc, out);
    } else {
        dim3 grid(MT / 16, ND / 16);
        hipLaunchKernelGGL(k_fallback, grid, dim3(16, 16), 0, stream, x, w, sc, out);
    }
}